// Round 1
// baseline (576.987 us; speedup 1.0000x reference)
//
#include <hip/hip_runtime.h>
#include <math.h>

#define BATCH 4096
#define D1 2048
#define D2 1024
#define DF 8192
#define LOG2N 13
#define NTHREADS 512
#define EPT (DF / NTHREADS)   /* 16 */
#define NWAVES (NTHREADS / 64)

__device__ __forceinline__ int brev13(int k) {
    return (int)(__brev((unsigned)k) >> (32 - LOG2N));
}

__global__ __launch_bounds__(NTHREADS)
void mcb_fused_kernel(const float* __restrict__ x, const float* __restrict__ y,
                      const float* __restrict__ s1, const float* __restrict__ s2,
                      const float* __restrict__ gamma, const float* __restrict__ beta,
                      const int* __restrict__ h1, const int* __restrict__ h2,
                      float* __restrict__ out)
{
    __shared__ float2 z[DF];   // 64 KB: packed complex work array
    const int tid = threadIdx.x;
    const int row = blockIdx.x;

    // ---- zero LDS ----
    #pragma unroll
    for (int c = 0; c < EPT; ++c)
        z[tid + c * NTHREADS] = make_float2(0.f, 0.f);
    __syncthreads();

    // ---- count sketches: x*s1 -> real, y*s2 -> imag ----
    {
        const float* xr = x + (size_t)row * D1;
        #pragma unroll
        for (int c = 0; c < D1 / NTHREADS; ++c) {
            int i = tid + c * NTHREADS;
            atomicAdd(&z[h1[i]].x, xr[i] * s1[i]);
        }
        const float* yr = y + (size_t)row * D2;
        #pragma unroll
        for (int c = 0; c < D2 / NTHREADS; ++c) {
            int i = tid + c * NTHREADS;
            atomicAdd(&z[h2[i]].y, yr[i] * s2[i]);
        }
    }
    __syncthreads();

    // ---- forward radix-2 DIF FFT (natural -> bit-reversed), w = e^{-i*pi*t/h} ----
    for (int s = 0; s < LOG2N; ++s) {
        const int lh = LOG2N - 1 - s;
        const int h = 1 << lh;
        #pragma unroll
        for (int c = 0; c < DF / 2 / NTHREADS; ++c) {   // 8 butterflies/thread
            int q = tid + c * NTHREADS;
            int t = q & (h - 1);
            int i = ((q >> lh) << (lh + 1)) | t;
            int j = i + h;
            float2 a = z[i], b = z[j];
            float sr = a.x + b.x, si = a.y + b.y;
            float dr = a.x - b.x, di = a.y - b.y;
            float ang = -(float)M_PI * (float)t / (float)h;
            float sn, cs;
            __sincosf(ang, &sn, &cs);
            z[i] = make_float2(sr, si);
            z[j] = make_float2(dr * cs - di * sn, dr * sn + di * cs);
        }
        __syncthreads();
    }

    // ---- Hermitian extraction + pointwise product (x 1/N), bit-reversed in-place ----
    {
        const float invN = 1.0f / (float)DF;
        #pragma unroll
        for (int c = 0; c < DF / 2 / NTHREADS; ++c) {
            int k  = tid + c * NTHREADS;          // 0..4095
            int k2 = (DF - k) & (DF - 1);
            int p  = brev13(k), p2 = brev13(k2);
            float2 a = z[p], b = z[p2];
            // X = (a + conj b)/2 ; Y = -i(a - conj b)/2
            float Xr = 0.5f * (a.x + b.x), Xi = 0.5f * (a.y - b.y);
            float Yr = 0.5f * (a.y + b.y), Yi = 0.5f * (b.x - a.x);
            float Wr = (Xr * Yr - Xi * Yi) * invN;
            float Wi = (Xr * Yi + Xi * Yr) * invN;
            z[p]  = make_float2(Wr,  Wi);
            z[p2] = make_float2(Wr, -Wi);
        }
        if (tid == 0) {  // k = N/2 self-paired bin
            int p = brev13(DF / 2);
            float2 a = z[p];
            z[p] = make_float2(a.x * a.y * invN, 0.f);
        }
    }
    __syncthreads();

    // ---- inverse radix-2 DIT FFT (bit-reversed -> natural), w = e^{+i*pi*t/h} ----
    for (int s = 0; s < LOG2N; ++s) {
        const int lh = s;
        const int h = 1 << lh;
        #pragma unroll
        for (int c = 0; c < DF / 2 / NTHREADS; ++c) {
            int q = tid + c * NTHREADS;
            int t = q & (h - 1);
            int i = ((q >> lh) << (lh + 1)) | t;
            int j = i + h;
            float2 a = z[i], b = z[j];
            float ang = (float)M_PI * (float)t / (float)h;
            float sn, cs;
            __sincosf(ang, &sn, &cs);
            float br_ = b.x * cs - b.y * sn;
            float bi_ = b.x * sn + b.y * cs;
            z[i] = make_float2(a.x + br_, a.y + bi_);
            z[j] = make_float2(a.x - br_, a.y - bi_);
        }
        __syncthreads();
    }

    // ---- LayerNorm + L2 normalize (fused real part lives in z[k].x) ----
    float v[EPT];
    float lsum = 0.f, lsq = 0.f;
    #pragma unroll
    for (int c = 0; c < EPT; ++c) {
        float f = z[tid + c * NTHREADS].x;
        v[c] = f;
        lsum += f;
        lsq  += f * f;
    }
    #pragma unroll
    for (int m = 32; m >= 1; m >>= 1) {
        lsum += __shfl_xor(lsum, m);
        lsq  += __shfl_xor(lsq,  m);
    }
    const int wid = tid >> 6, lane = tid & 63;
    if (lane == 0) { z[wid].y = lsum; z[NWAVES + wid].y = lsq; }  // stash in unused .y
    __syncthreads();
    float tsum = 0.f, tsq = 0.f;
    #pragma unroll
    for (int w = 0; w < NWAVES; ++w) { tsum += z[w].y; tsq += z[NWAVES + w].y; }
    const float mu   = tsum * (1.0f / (float)DF);
    const float var  = tsq * (1.0f / (float)DF) - mu * mu;
    const float rstd = rsqrtf(var + 1e-5f);

    float lsq2 = 0.f;
    #pragma unroll
    for (int c = 0; c < EPT; ++c) {
        int k = tid + c * NTHREADS;
        float nv = (v[c] - mu) * rstd * gamma[k] + beta[k];
        v[c] = nv;
        lsq2 += nv * nv;
    }
    #pragma unroll
    for (int m = 32; m >= 1; m >>= 1) lsq2 += __shfl_xor(lsq2, m);
    if (lane == 0) z[2 * NWAVES + wid].y = lsq2;
    __syncthreads();
    float t2 = 0.f;
    #pragma unroll
    for (int w = 0; w < NWAVES; ++w) t2 += z[2 * NWAVES + w].y;
    const float inv = 1.0f / fmaxf(sqrtf(t2), 1e-12f);

    float* orow = out + (size_t)row * DF;
    #pragma unroll
    for (int c = 0; c < EPT; ++c)
        orow[tid + c * NTHREADS] = v[c] * inv;
}

extern "C" void kernel_launch(void* const* d_in, const int* in_sizes, int n_in,
                              void* d_out, int out_size, void* d_ws, size_t ws_size,
                              hipStream_t stream) {
    const float* x     = (const float*)d_in[0];
    const float* y     = (const float*)d_in[1];
    const float* s1    = (const float*)d_in[2];
    const float* s2    = (const float*)d_in[3];
    const float* gamma = (const float*)d_in[4];
    const float* beta  = (const float*)d_in[5];
    const int*   h1    = (const int*)d_in[6];
    const int*   h2    = (const int*)d_in[7];
    float* out = (float*)d_out;

    hipLaunchKernelGGL(mcb_fused_kernel, dim3(BATCH), dim3(NTHREADS), 0, stream,
                       x, y, s1, s2, gamma, beta, h1, h2, out);
}

// Round 2
// 195.315 us; speedup vs baseline: 2.9541x; 2.9541x over previous
//
#include <hip/hip_runtime.h>
#include <math.h>

#define BATCH 4096
#define D1 2048
#define D2 1024
#define DF 8192
#define NT 512

// pad 1 float per 32 to kill power-of-2 bank aliasing
#define PADI(i) ((i) + ((i) >> 5))

__device__ __forceinline__ float2 cmul(float2 a, float2 b) {
    return make_float2(a.x * b.x - a.y * b.y, a.x * b.y + a.y * b.x);
}
__device__ __forceinline__ float2 cadd(float2 a, float2 b) { return make_float2(a.x + b.x, a.y + b.y); }
__device__ __forceinline__ float2 csub(float2 a, float2 b) { return make_float2(a.x - b.x, a.y - b.y); }

#define RT_C 0.92387953251128674f
#define RT_S 0.38268343236508977f
#define RT_H 0.70710678118654752f

__device__ __forceinline__ float2 rootF(int j) {   // exp(-i*pi*j/8)
    switch (j & 7) {
        case 0:  return make_float2( 1.f,   0.f  );
        case 1:  return make_float2( RT_C, -RT_S );
        case 2:  return make_float2( RT_H, -RT_H );
        case 3:  return make_float2( RT_S, -RT_C );
        case 4:  return make_float2( 0.f,  -1.f  );
        case 5:  return make_float2(-RT_S, -RT_C );
        case 6:  return make_float2(-RT_H, -RT_H );
        default: return make_float2(-RT_C, -RT_S );
    }
}
__device__ __forceinline__ float2 rootI(int j) {   // exp(+i*pi*j/8)
    float2 r = rootF(j);
    return make_float2(r.x, -r.y);
}

__device__ __forceinline__ int brev4c(int x) {
    return ((x & 1) << 3) | ((x & 2) << 1) | ((x & 4) >> 1) | ((x & 8) >> 3);
}
__device__ __forceinline__ int brev9(int x) {
    return (int)(__brev((unsigned)x) >> 23);
}

// 4 radix-2 DIF stages on 16 register-resident elements.
// Twiddles: stage1 (m,m+8): wb*rootF(m); stage2 (m,m+4): wb^2*rootF(2m);
// stage3 (m,m+2): wb^4*rootF(4m); stage4 (m,m+1): wb^8.
__device__ __forceinline__ void fft16_dif(float2 v[16], float2 wb) {
    const float2 wb2 = cmul(wb, wb);
    const float2 wb4 = cmul(wb2, wb2);
    const float2 wb8 = cmul(wb4, wb4);
    #pragma unroll
    for (int m = 0; m < 8; ++m) {
        float2 W = cmul(wb, rootF(m));
        float2 a = v[m], b = v[m + 8];
        v[m] = cadd(a, b);
        v[m + 8] = cmul(csub(a, b), W);
    }
    #pragma unroll
    for (int g = 0; g < 2; ++g)
        #pragma unroll
        for (int m = 0; m < 4; ++m) {
            int i = 8 * g + m;
            float2 W = cmul(wb2, rootF(2 * m));
            float2 a = v[i], b = v[i + 4];
            v[i] = cadd(a, b);
            v[i + 4] = cmul(csub(a, b), W);
        }
    #pragma unroll
    for (int g = 0; g < 4; ++g)
        #pragma unroll
        for (int m = 0; m < 2; ++m) {
            int i = 4 * g + m;
            float2 W = cmul(wb4, rootF(4 * m));
            float2 a = v[i], b = v[i + 2];
            v[i] = cadd(a, b);
            v[i + 2] = cmul(csub(a, b), W);
        }
    #pragma unroll
    for (int g = 0; g < 8; ++g) {
        int i = 2 * g;
        float2 a = v[i], b = v[i + 1];
        v[i] = cadd(a, b);
        v[i + 1] = cmul(csub(a, b), wb8);
    }
}

// 4 radix-2 DIT stages (smallest h first), twiddle on 2nd input before add/sub.
__device__ __forceinline__ void fft16_dit(float2 v[16], float2 wb) {
    const float2 wb2 = cmul(wb, wb);
    const float2 wb4 = cmul(wb2, wb2);
    const float2 wb8 = cmul(wb4, wb4);
    #pragma unroll
    for (int g = 0; g < 8; ++g) {
        int i = 2 * g;
        float2 a = v[i], b = cmul(v[i + 1], wb8);
        v[i] = cadd(a, b);
        v[i + 1] = csub(a, b);
    }
    #pragma unroll
    for (int g = 0; g < 4; ++g)
        #pragma unroll
        for (int m = 0; m < 2; ++m) {
            int i = 4 * g + m;
            float2 W = cmul(wb4, rootI(4 * m));
            float2 a = v[i], b = cmul(v[i + 2], W);
            v[i] = cadd(a, b);
            v[i + 2] = csub(a, b);
        }
    #pragma unroll
    for (int g = 0; g < 2; ++g)
        #pragma unroll
        for (int m = 0; m < 4; ++m) {
            int i = 8 * g + m;
            float2 W = cmul(wb2, rootI(2 * m));
            float2 a = v[i], b = cmul(v[i + 4], W);
            v[i] = cadd(a, b);
            v[i + 4] = csub(a, b);
        }
    #pragma unroll
    for (int m = 0; m < 8; ++m) {
        float2 W = cmul(wb, rootI(m));
        float2 a = v[m], b = cmul(v[m + 8], W);
        v[m] = cadd(a, b);
        v[m + 8] = csub(a, b);
    }
}

__global__ __launch_bounds__(NT, 4)
void mcb_fused2(const float* __restrict__ x, const float* __restrict__ y,
                const float* __restrict__ s1, const float* __restrict__ s2,
                const float* __restrict__ gamma, const float* __restrict__ beta,
                const int* __restrict__ h1, const int* __restrict__ h2,
                float* __restrict__ out)
{
    __shared__ float re[DF + DF / 32];
    __shared__ float im[DF + DF / 32];
    const int t = threadIdx.x;
    const int row = blockIdx.x;

    // ---- zero ----
    #pragma unroll
    for (int m = 0; m < 16; ++m) {
        int p = PADI(t + NT * m);
        re[p] = 0.f; im[p] = 0.f;
    }
    __syncthreads();

    // ---- count sketches: x*s1 -> re, y*s2 -> im ----
    {
        const float* xr = x + (size_t)row * D1;
        #pragma unroll
        for (int c = 0; c < D1 / NT; ++c) {
            int i = t + NT * c;
            atomicAdd(&re[PADI(h1[i])], xr[i] * s1[i]);
        }
        const float* yr = y + (size_t)row * D2;
        #pragma unroll
        for (int c = 0; c < D2 / NT; ++c) {
            int i = t + NT * c;
            atomicAdd(&im[PADI(h2[i])], yr[i] * s2[i]);
        }
    }
    __syncthreads();

    float2 v[16];
    float sn, cs;

    // ---------- forward G1: h=4096..512, idx = t + 512m ----------
    #pragma unroll
    for (int m = 0; m < 16; ++m) {
        int p = PADI(t + 512 * m);
        v[m] = make_float2(re[p], im[p]);
    }
    __sincosf(-(float)M_PI / 4096.f * (float)t, &sn, &cs);
    fft16_dif(v, make_float2(cs, sn));
    #pragma unroll
    for (int m = 0; m < 16; ++m) {
        int p = PADI(t + 512 * m);
        re[p] = v[m].x; im[p] = v[m].y;
    }
    __syncthreads();

    // ---------- forward G2: h=256..32, idx = lo + 32m + 512hi ----------
    {
        const int lo = t & 31, hi = t >> 5;
        #pragma unroll
        for (int m = 0; m < 16; ++m) {
            int p = PADI(lo + 32 * m + 512 * hi);
            v[m] = make_float2(re[p], im[p]);
        }
        __sincosf(-(float)M_PI / 256.f * (float)lo, &sn, &cs);
        fft16_dif(v, make_float2(cs, sn));
        #pragma unroll
        for (int m = 0; m < 16; ++m) {
            int p = PADI(lo + 32 * m + 512 * hi);
            re[p] = v[m].x; im[p] = v[m].y;
        }
    }
    __syncthreads();

    // ---------- forward G3: h=16..2, idx = lo + 2m + 32hi ----------
    {
        const int lo = t & 1, hi = t >> 1;
        #pragma unroll
        for (int m = 0; m < 16; ++m) {
            int p = PADI(lo + 2 * m + 32 * hi);
            v[m] = make_float2(re[p], im[p]);
        }
        __sincosf(-(float)M_PI / 16.f * (float)lo, &sn, &cs);
        fft16_dif(v, make_float2(cs, sn));
        #pragma unroll
        for (int m = 0; m < 16; ++m) {
            int p = PADI(lo + 2 * m + 32 * hi);
            re[p] = v[m].x; im[p] = v[m].y;
        }
    }
    __syncthreads();

    // ---------- forward G4: h=1, idx = 16t + m (registers end at positions 16t+m) ----------
    #pragma unroll
    for (int m = 0; m < 16; ++m) {
        int p = PADI(16 * t + m);
        v[m] = make_float2(re[p], im[p]);
    }
    #pragma unroll
    for (int g = 0; g < 8; ++g) {
        float2 a = v[2 * g], b = v[2 * g + 1];
        v[2 * g] = cadd(a, b);
        v[2 * g + 1] = csub(a, b);
    }
    #pragma unroll
    for (int m = 0; m < 16; ++m) {
        int p = PADI(16 * t + m);
        re[p] = v[m].x; im[p] = v[m].y;
    }
    __syncthreads();

    // ---------- Hermitian extract + pointwise product + inverse G1' (in regs) ----------
    // position p=16t+m holds X[k], k = 512*brev4(m) + brev9(t); partner block is
    // c2 = brev9(512-brev9(t)) (c2=0 if t==0); self-paired bins k=0,4096 degenerate OK.
    {
        const float invN = 1.f / (float)DF;
        const int R = brev9(t);
        const int c2 = (R == 0) ? 0 : brev9(512 - R);
        #pragma unroll
        for (int m = 0; m < 16; ++m) {
            int M = brev4c(m);
            int M2 = (R == 0) ? ((16 - M) & 15) : (15 - M);
            int p2 = PADI(16 * c2 + brev4c(M2));
            float2 a = v[m];
            float2 b = make_float2(re[p2], im[p2]);
            float Xr = 0.5f * (a.x + b.x), Xi = 0.5f * (a.y - b.y);
            float Yr = 0.5f * (a.y + b.y), Yi = 0.5f * (b.x - a.x);
            v[m] = make_float2((Xr * Yr - Xi * Yi) * invN,
                               (Xr * Yi + Xi * Yr) * invN);
        }
        fft16_dit(v, make_float2(1.f, 0.f));   // inverse stages h=1,2,4,8
    }
    __syncthreads();   // all partner reads done before overwriting
    #pragma unroll
    for (int m = 0; m < 16; ++m) {
        int p = PADI(16 * t + m);
        re[p] = v[m].x; im[p] = v[m].y;
    }
    __syncthreads();

    // ---------- inverse G2': h=16..128, idx = lo + 16m + 256hi ----------
    {
        const int lo = t & 15, hi = t >> 4;
        #pragma unroll
        for (int m = 0; m < 16; ++m) {
            int p = PADI(lo + 16 * m + 256 * hi);
            v[m] = make_float2(re[p], im[p]);
        }
        __sincosf((float)M_PI / 128.f * (float)lo, &sn, &cs);
        fft16_dit(v, make_float2(cs, sn));
        #pragma unroll
        for (int m = 0; m < 16; ++m) {
            int p = PADI(lo + 16 * m + 256 * hi);
            re[p] = v[m].x; im[p] = v[m].y;
        }
    }
    __syncthreads();

    // ---------- inverse G3': h=256..2048, idx = lo + 256m + 4096hi ----------
    {
        const int lo = t & 255, hi = t >> 8;
        #pragma unroll
        for (int m = 0; m < 16; ++m) {
            int p = PADI(lo + 256 * m + 4096 * hi);
            v[m] = make_float2(re[p], im[p]);
        }
        __sincosf((float)M_PI / 2048.f * (float)lo, &sn, &cs);
        fft16_dit(v, make_float2(cs, sn));
        #pragma unroll
        for (int m = 0; m < 16; ++m) {
            int p = PADI(lo + 256 * m + 4096 * hi);
            re[p] = v[m].x; im[p] = v[m].y;
        }
    }
    __syncthreads();

    // ---------- inverse G4': h=4096, idx = t + 512m; then LN + L2 from regs ----------
    #pragma unroll
    for (int m = 0; m < 16; ++m) {
        int p = PADI(t + 512 * m);
        v[m] = make_float2(re[p], im[p]);
    }
    __sincosf((float)M_PI / 4096.f * (float)t, &sn, &cs);
    {
        float2 wb = make_float2(cs, sn);
        #pragma unroll
        for (int m = 0; m < 8; ++m) {
            float2 W = cmul(wb, rootI(m));
            float2 a = v[m], b = cmul(v[m + 8], W);
            v[m] = cadd(a, b);
            v[m + 8] = csub(a, b);
        }
    }

    float lsum = 0.f, lsq = 0.f;
    #pragma unroll
    for (int m = 0; m < 16; ++m) { float f = v[m].x; lsum += f; lsq += f * f; }
    #pragma unroll
    for (int k = 32; k >= 1; k >>= 1) { lsum += __shfl_xor(lsum, k); lsq += __shfl_xor(lsq, k); }
    const int wid = t >> 6, lane = t & 63;
    __syncthreads();                 // all G4' LDS reads complete before stash
    if (lane == 0) { re[wid] = lsum; re[8 + wid] = lsq; }
    __syncthreads();
    float tsum = 0.f, tsq = 0.f;
    #pragma unroll
    for (int w = 0; w < 8; ++w) { tsum += re[w]; tsq += re[8 + w]; }
    const float mu = tsum * (1.f / (float)DF);
    const float var = tsq * (1.f / (float)DF) - mu * mu;
    const float rstd = rsqrtf(var + 1e-5f);

    float lsq2 = 0.f;
    #pragma unroll
    for (int m = 0; m < 16; ++m) {
        int i = t + 512 * m;
        float nv = (v[m].x - mu) * rstd * gamma[i] + beta[i];
        v[m].x = nv;
        lsq2 += nv * nv;
    }
    #pragma unroll
    for (int k = 32; k >= 1; k >>= 1) lsq2 += __shfl_xor(lsq2, k);
    if (lane == 0) re[16 + wid] = lsq2;
    __syncthreads();
    float t2 = 0.f;
    #pragma unroll
    for (int w = 0; w < 8; ++w) t2 += re[16 + w];
    const float inv = 1.f / fmaxf(sqrtf(t2), 1e-12f);

    float* orow = out + (size_t)row * DF;
    #pragma unroll
    for (int m = 0; m < 16; ++m)
        orow[t + 512 * m] = v[m].x * inv;
}

extern "C" void kernel_launch(void* const* d_in, const int* in_sizes, int n_in,
                              void* d_out, int out_size, void* d_ws, size_t ws_size,
                              hipStream_t stream) {
    const float* x     = (const float*)d_in[0];
    const float* y     = (const float*)d_in[1];
    const float* s1    = (const float*)d_in[2];
    const float* s2    = (const float*)d_in[3];
    const float* gamma = (const float*)d_in[4];
    const float* beta  = (const float*)d_in[5];
    const int*   h1    = (const int*)d_in[6];
    const int*   h2    = (const int*)d_in[7];
    float* out = (float*)d_out;

    hipLaunchKernelGGL(mcb_fused2, dim3(BATCH), dim3(NT), 0, stream,
                       x, y, s1, s2, gamma, beta, h1, h2, out);
}

// Round 3
// 180.257 us; speedup vs baseline: 3.2009x; 1.0835x over previous
//
#include <hip/hip_runtime.h>
#include <math.h>

#define DF 8192
#define NT 512

// XOR swizzle on float2 index, bits 1..3 only (keeps float4 pairs adjacent+ordered)
#define PH(i) ((i) ^ (((i) >> 5) & 14))

__device__ __forceinline__ float2 cmul(float2 a, float2 b) {
    return make_float2(a.x * b.x - a.y * b.y, a.x * b.y + a.y * b.x);
}
__device__ __forceinline__ float2 cadd(float2 a, float2 b) { return make_float2(a.x + b.x, a.y + b.y); }
__device__ __forceinline__ float2 csub(float2 a, float2 b) { return make_float2(a.x - b.x, a.y - b.y); }
__device__ __forceinline__ float2 cmuli(float2 a) { return make_float2(-a.y, a.x); }   // a * i

#define RT_C 0.92387953251128674f
#define RT_S 0.38268343236508977f
#define RT_H 0.70710678118654752f

__device__ __forceinline__ float2 rootF(int j) {   // exp(-i*pi*j/8)
    switch (j & 7) {
        case 0:  return make_float2( 1.f,   0.f  );
        case 1:  return make_float2( RT_C, -RT_S );
        case 2:  return make_float2( RT_H, -RT_H );
        case 3:  return make_float2( RT_S, -RT_C );
        case 4:  return make_float2( 0.f,  -1.f  );
        case 5:  return make_float2(-RT_S, -RT_C );
        case 6:  return make_float2(-RT_H, -RT_H );
        default: return make_float2(-RT_C, -RT_S );
    }
}
__device__ __forceinline__ float2 rootI(int j) {   // exp(+i*pi*j/8)
    float2 r = rootF(j);
    return make_float2(r.x, -r.y);
}

__device__ __forceinline__ int brev9(int x) { return (int)(__brev((unsigned)x) >> 23); }

// 4 radix-2 DIF stages on 16 register elements, base twiddle wb.
__device__ __forceinline__ void fft16_dif(float2 v[16], float2 wb) {
    const float2 wb2 = cmul(wb, wb);
    const float2 wb4 = cmul(wb2, wb2);
    const float2 wb8 = cmul(wb4, wb4);
    #pragma unroll
    for (int m = 0; m < 8; ++m) {
        float2 W = cmul(wb, rootF(m));
        float2 a = v[m], b = v[m + 8];
        v[m] = cadd(a, b);
        v[m + 8] = cmul(csub(a, b), W);
    }
    #pragma unroll
    for (int g = 0; g < 2; ++g)
        #pragma unroll
        for (int m = 0; m < 4; ++m) {
            int i = 8 * g + m;
            float2 W = cmul(wb2, rootF(2 * m));
            float2 a = v[i], b = v[i + 4];
            v[i] = cadd(a, b);
            v[i + 4] = cmul(csub(a, b), W);
        }
    #pragma unroll
    for (int g = 0; g < 4; ++g)
        #pragma unroll
        for (int m = 0; m < 2; ++m) {
            int i = 4 * g + m;
            float2 W = cmul(wb4, rootF(4 * m));
            float2 a = v[i], b = v[i + 2];
            v[i] = cadd(a, b);
            v[i + 2] = cmul(csub(a, b), W);
        }
    #pragma unroll
    for (int g = 0; g < 8; ++g) {
        int i = 2 * g;
        float2 a = v[i], b = v[i + 1];
        v[i] = cadd(a, b);
        v[i + 1] = cmul(csub(a, b), wb8);
    }
}

__device__ __forceinline__ void bf_dit(float2& a, float2& b, float2 W) {
    float2 bw = cmul(b, W);
    float2 ta = a;
    a = cadd(ta, bw);
    b = csub(ta, bw);
}
__device__ __forceinline__ void bf_dit1(float2& a, float2& b) {     // W = 1
    float2 tb = b, ta = a;
    a = cadd(ta, tb);
    b = csub(ta, tb);
}
__device__ __forceinline__ void bf_diti(float2& a, float2& b) {     // W = i
    float2 bw = cmuli(b);
    float2 ta = a;
    a = cadd(ta, bw);
    b = csub(ta, bw);
}

// 3 radix-2 DIT stages on 8 register elements; wq = exp(+i*pi*lo/(4*hmin)) where
// first stage's actual half-size hmin gives W_hmin = wq^4.
__device__ __forceinline__ void fft8_dit(float2 v[8], float2 wq) {
    const float2 wq2 = cmul(wq, wq);
    const float2 wq4 = cmul(wq2, wq2);
    #pragma unroll
    for (int g = 0; g < 4; ++g) bf_dit(v[2 * g], v[2 * g + 1], wq4);
    #pragma unroll
    for (int g = 0; g < 2; ++g) {
        bf_dit(v[4 * g],     v[4 * g + 2], wq2);
        bf_dit(v[4 * g + 1], v[4 * g + 3], cmuli(wq2));
    }
    bf_dit(v[0], v[4], wq);
    bf_dit(v[1], v[5], cmul(wq, make_float2(RT_H, RT_H)));
    bf_dit(v[2], v[6], cmuli(wq));
    bf_dit(v[3], v[7], cmul(wq, make_float2(-RT_H, RT_H)));
}

// same with wq = 1 (all-trivial/constant twiddles)
__device__ __forceinline__ void fft8_dit1(float2 v[8]) {
    #pragma unroll
    for (int g = 0; g < 4; ++g) bf_dit1(v[2 * g], v[2 * g + 1]);
    #pragma unroll
    for (int g = 0; g < 2; ++g) {
        bf_dit1(v[4 * g],     v[4 * g + 2]);
        bf_diti(v[4 * g + 1], v[4 * g + 3]);
    }
    bf_dit1(v[0], v[4]);
    bf_dit (v[1], v[5], make_float2(RT_H, RT_H));
    bf_diti(v[2], v[6]);
    bf_dit (v[3], v[7], make_float2(-RT_H, RT_H));
}

__global__ __launch_bounds__(NT, 4)
void mcb3(const float* __restrict__ x, const float* __restrict__ y,
          const float* __restrict__ s1, const float* __restrict__ s2,
          const float* __restrict__ gamma, const float* __restrict__ beta,
          const int* __restrict__ h1, const int* __restrict__ h2,
          float* __restrict__ out)
{
    __shared__ float2 z[DF];   // 64 KB
    const int t = threadIdx.x;
    const int row = blockIdx.x;

    // ---- zero (raw slots; PH is a bijection) ----
    #pragma unroll
    for (int m = 0; m < 16; ++m) z[t + NT * m] = make_float2(0.f, 0.f);
    __syncthreads();

    // ---- count sketches: x*s1 -> .x, y*s2 -> .y (vectorized loads) ----
    {
        const float4* x4  = (const float4*)(x + (size_t)row * 2048);
        const float4* s14 = (const float4*)s1;
        const int4*   h14 = (const int4*)h1;
        float4 xv = x4[t], sv = s14[t];
        int4 hv = h14[t];
        atomicAdd(&z[PH(hv.x)].x, xv.x * sv.x);
        atomicAdd(&z[PH(hv.y)].x, xv.y * sv.y);
        atomicAdd(&z[PH(hv.z)].x, xv.z * sv.z);
        atomicAdd(&z[PH(hv.w)].x, xv.w * sv.w);
        const float2* y2  = (const float2*)(y + (size_t)row * 1024);
        const float2* s22 = (const float2*)s2;
        const int2*   h22 = (const int2*)h2;
        float2 yv = y2[t], tv = s22[t];
        int2 hw = h22[t];
        atomicAdd(&z[PH(hw.x)].y, yv.x * tv.x);
        atomicAdd(&z[PH(hw.y)].y, yv.y * tv.y);
    }
    __syncthreads();

    float sn, cs;

    // ---------- forward G1: h=4096..512, idx = t + 512m ----------
    {
        float2 v[16];
        #pragma unroll
        for (int m = 0; m < 16; ++m) v[m] = z[PH(t + 512 * m)];
        __sincosf(-(float)M_PI / 4096.f * (float)t, &sn, &cs);
        fft16_dif(v, make_float2(cs, sn));
        #pragma unroll
        for (int m = 0; m < 16; ++m) z[PH(t + 512 * m)] = v[m];
    }
    __syncthreads();

    // ---------- forward G2: h=256..32, idx = lo + 32m + 512hi ----------
    {
        const int lo = t & 31, hi = t >> 5;
        float2 v[16];
        #pragma unroll
        for (int m = 0; m < 16; ++m) v[m] = z[PH(lo + 32 * m + 512 * hi)];
        __sincosf(-(float)M_PI / 256.f * (float)lo, &sn, &cs);
        fft16_dif(v, make_float2(cs, sn));
        #pragma unroll
        for (int m = 0; m < 16; ++m) z[PH(lo + 32 * m + 512 * hi)] = v[m];
    }
    __syncthreads();

    // ---------- forward G3: h=16..2, idx = lo + 2m + 32hi ----------
    {
        const int lo = t & 1, hi = t >> 1;
        float2 v[16];
        #pragma unroll
        for (int m = 0; m < 16; ++m) v[m] = z[PH(lo + 2 * m + 32 * hi)];
        __sincosf(-(float)M_PI / 16.f * (float)lo, &sn, &cs);
        fft16_dif(v, make_float2(cs, sn));
        #pragma unroll
        for (int m = 0; m < 16; ++m) z[PH(lo + 2 * m + 32 * hi)] = v[m];
    }
    __syncthreads();

    // ---------- MEGA: stage13 + Hermitian product + U-prep + inverse S1 ----------
    // After 12 stages, pos p holds pre-stage13 data; pairs (2jp,2jp+1), jp=8t+m.
    // Post-stage13: even slot = Z[kappa], odd = Z[kappa+4096], kappa = 512*brev3(m)+brev9(t).
    // Hermitian partner pair lives at jp' = 8*brev9(512-R) + (7-m).
    float2 u8[8];     // carries U through inverse sweeps
    {
        const int R  = brev9(t);
        const int tp = brev9((512 - R) & 511);
        float2 a[8], b[8], pa[8], pb[8];
        #pragma unroll
        for (int m = 0; m < 8; ++m) {
            float4 q = *(const float4*)&z[PH(16 * t + 2 * m)];
            a[m] = make_float2(q.x, q.y);  b[m] = make_float2(q.z, q.w);
            float4 qp = *(const float4*)&z[PH(16 * tp + 2 * (7 - m))];
            pa[m] = make_float2(qp.x, qp.y); pb[m] = make_float2(qp.z, qp.w);
        }
        // stage-13 butterflies (W = 1) on own and partner pairs
        #pragma unroll
        for (int m = 0; m < 8; ++m) {
            float2 ta = a[m],  tb = b[m];
            a[m] = cadd(ta, tb);  b[m] = csub(ta, tb);
            ta = pa[m]; tb = pb[m];
            pa[m] = cadd(ta, tb); pb[m] = csub(ta, tb);
        }
        if (t == 0) {   // self-referential partners for R=0 (one lane diverges)
            float2 ca[8], cb[8];
            #pragma unroll
            for (int m = 0; m < 8; ++m) { ca[m] = a[m]; cb[m] = b[m]; }
            const int tbl[8] = {0, 1, 3, 2, 7, 6, 5, 4};
            #pragma unroll
            for (int m = 0; m < 8; ++m) {
                if (m == 0) { pa[0] = cb[0]; pb[0] = ca[0]; }   // kappa=0: swapped own pair
                else        { pa[m] = ca[tbl[m]]; pb[m] = cb[tbl[m]]; }
            }
        }
        __sincosf((float)M_PI / 4096.f * (float)R, &sn, &cs);
        const float2 wR = make_float2(cs, sn);    // exp(+i*pi*R/4096)
        const float invN = 1.f / 8192.f;
        const int MB[8] = {0, 4, 2, 6, 1, 5, 3, 7};   // brev3(m)
        #pragma unroll
        for (int m = 0; m < 8; ++m) {
            float2 A = a[m], B = b[m], A2 = pa[m], B2 = pb[m];
            // P1 = X[k]Y[k]/N at k=kappa   (X=(A+conj B2)/2, Y=-i(A-conj B2)/2)
            float X1r = 0.5f * (A.x + B2.x), X1i = 0.5f * (A.y - B2.y);
            float Y1r = 0.5f * (A.y + B2.y), Y1i = 0.5f * (B2.x - A.x);
            float2 P1 = make_float2((X1r * Y1r - X1i * Y1i) * invN,
                                    (X1r * Y1i + X1i * Y1r) * invN);
            // P2 at k=kappa+4096   (X=(B+conj A2)/2, Y=-i(B-conj A2)/2)
            float X2r = 0.5f * (B.x + A2.x), X2i = 0.5f * (B.y - A2.y);
            float Y2r = 0.5f * (B.y + A2.y), Y2i = 0.5f * (A2.x - B.x);
            float2 P2 = make_float2((X2r * Y2r - X2i * Y2i) * invN,
                                    (X2r * Y2i + X2i * Y2r) * invN);
            // U = (P1+P2) + i*(P1-P2)*W,  W = wR * rootI(brev3(m))
            float2 S = cadd(P1, P2);
            float2 D = csub(P1, P2);
            float2 Dw = cmul(D, cmul(wR, rootI(MB[m])));
            u8[m] = make_float2(S.x - Dw.y, S.y + Dw.x);
        }
        fft8_dit1(u8);            // inverse stages h=1,2,4 (compile-time twiddles)
        __syncthreads();          // all pair/partner reads complete before overwrite
        #pragma unroll
        for (int g = 0; g < 4; ++g) {
            *(float4*)&z[PH(8 * t + 2 * g)] =
                make_float4(u8[2 * g].x, u8[2 * g].y, u8[2 * g + 1].x, u8[2 * g + 1].y);
        }
    }
    __syncthreads();

    // ---------- inverse S2: h=8,16,32, idx = lo + 8m + 64hi ----------
    {
        const int lo = t & 7, hi = t >> 3;
        #pragma unroll
        for (int m = 0; m < 8; ++m) u8[m] = z[PH(lo + 8 * m + 64 * hi)];
        __sincosf((float)M_PI / 32.f * (float)lo, &sn, &cs);
        fft8_dit(u8, make_float2(cs, sn));
        #pragma unroll
        for (int m = 0; m < 8; ++m) z[PH(lo + 8 * m + 64 * hi)] = u8[m];
    }
    __syncthreads();

    // ---------- inverse S3: h=64,128,256, idx = lo + 64m + 512hi ----------
    {
        const int lo = t & 63, hi = t >> 6;
        #pragma unroll
        for (int m = 0; m < 8; ++m) u8[m] = z[PH(lo + 64 * m + 512 * hi)];
        __sincosf((float)M_PI / 256.f * (float)lo, &sn, &cs);
        fft8_dit(u8, make_float2(cs, sn));
        #pragma unroll
        for (int m = 0; m < 8; ++m) z[PH(lo + 64 * m + 512 * hi)] = u8[m];
    }
    __syncthreads();

    // ---------- inverse S4: h=512,1024,2048, idx = t + 512m; LN + L2 from regs ----------
    #pragma unroll
    for (int m = 0; m < 8; ++m) u8[m] = z[PH(t + 512 * m)];
    __sincosf((float)M_PI / 2048.f * (float)t, &sn, &cs);
    fft8_dit(u8, make_float2(cs, sn));
    // u8[m] = u[t+512m]: fused[2i] = .x, fused[2i+1] = .y

    float lsum = 0.f, lsq = 0.f;
    #pragma unroll
    for (int m = 0; m < 8; ++m) {
        lsum += u8[m].x + u8[m].y;
        lsq  += u8[m].x * u8[m].x + u8[m].y * u8[m].y;
    }
    #pragma unroll
    for (int k = 32; k >= 1; k >>= 1) { lsum += __shfl_xor(lsum, k); lsq += __shfl_xor(lsq, k); }
    const int wid = t >> 6, lane = t & 63;
    __syncthreads();                       // S4 reads complete before stash reuse
    if (lane == 0) z[wid] = make_float2(lsum, lsq);
    __syncthreads();
    float tsum = 0.f, tsq = 0.f;
    #pragma unroll
    for (int w = 0; w < 8; ++w) { tsum += z[w].x; tsq += z[w].y; }
    const float mu   = tsum * (1.f / (float)DF);
    const float var  = tsq * (1.f / (float)DF) - mu * mu;
    const float rstd = rsqrtf(var + 1e-5f);

    const float2* g2  = (const float2*)gamma;
    const float2* bt2 = (const float2*)beta;
    float2 nv[8];
    float lsq2 = 0.f;
    #pragma unroll
    for (int m = 0; m < 8; ++m) {
        int i = t + 512 * m;
        float2 g = g2[i], bb = bt2[i];
        float ne = (u8[m].x - mu) * rstd * g.x + bb.x;
        float no = (u8[m].y - mu) * rstd * g.y + bb.y;
        nv[m] = make_float2(ne, no);
        lsq2 += ne * ne + no * no;
    }
    #pragma unroll
    for (int k = 32; k >= 1; k >>= 1) lsq2 += __shfl_xor(lsq2, k);
    if (lane == 0) z[8 + wid].x = lsq2;
    __syncthreads();
    float t2 = 0.f;
    #pragma unroll
    for (int w = 0; w < 8; ++w) t2 += z[8 + w].x;
    const float inv = 1.f / fmaxf(sqrtf(t2), 1e-12f);

    float2* o2 = (float2*)(out + (size_t)row * DF);
    #pragma unroll
    for (int m = 0; m < 8; ++m)
        o2[t + 512 * m] = make_float2(nv[m].x * inv, nv[m].y * inv);
}

extern "C" void kernel_launch(void* const* d_in, const int* in_sizes, int n_in,
                              void* d_out, int out_size, void* d_ws, size_t ws_size,
                              hipStream_t stream) {
    const float* x     = (const float*)d_in[0];
    const float* y     = (const float*)d_in[1];
    const float* s1    = (const float*)d_in[2];
    const float* s2    = (const float*)d_in[3];
    const float* gamma = (const float*)d_in[4];
    const float* beta  = (const float*)d_in[5];
    const int*   h1    = (const int*)d_in[6];
    const int*   h2    = (const int*)d_in[7];
    float* out = (float*)d_out;

    hipLaunchKernelGGL(mcb3, dim3(4096), dim3(NT), 0, stream,
                       x, y, s1, s2, gamma, beta, h1, h2, out);
}